// Round 3
// baseline (634.585 us; speedup 1.0000x reference)
//
#include <hip/hip_runtime.h>
#include <hip/hip_bf16.h>

using bf16 = __hip_bfloat16;

#define NN 16384
#define NE 262144
#define ET (NE + NN)
#define NB 128
#define FEAT 78
#define HEADS 10
#define D1 780
#define OD 128
#define PL 1000
#define VOC 26
#define SLOPE 0.2f

// ---------------- CSR build ----------------
__global__ void k_hist(const int* __restrict__ ei, int* __restrict__ cnt){
    int e = blockIdx.x*256 + threadIdx.x;
    if (e >= ET) return;
    int dst = (e < NE) ? ei[NE + e] : (e - NE);
    atomicAdd(&cnt[dst], 1);
}

__global__ __launch_bounds__(1024) void k_scan(const int* __restrict__ cnt, int* __restrict__ off){
    __shared__ int ps[1024];
    int t = threadIdx.x;
    int loc[16]; int s = 0;
#pragma unroll
    for (int j = 0; j < 16; ++j){ loc[j] = cnt[t*16 + j]; s += loc[j]; }
    ps[t] = s; __syncthreads();
    for (int d = 1; d < 1024; d <<= 1){
        int v = (t >= d) ? ps[t - d] : 0;
        __syncthreads();
        ps[t] += v;
        __syncthreads();
    }
    int run = (t == 0) ? 0 : ps[t - 1];
#pragma unroll
    for (int j = 0; j < 16; ++j){ off[t*16 + j] = run; run += loc[j]; }
    if (t == 1023) off[NN] = run;
}

__global__ void k_fill(const int* __restrict__ ei, const int* __restrict__ off,
                       int* __restrict__ cur, int* __restrict__ csrc){
    int e = blockIdx.x*256 + threadIdx.x;
    if (e >= ET) return;
    int src, dst;
    if (e < NE){ src = ei[e]; dst = ei[NE + e]; } else { src = e - NE; dst = src; }
    int p = off[dst] + atomicAdd(&cur[dst], 1);
    csrc[p] = src;
}

// ---------------- GAT layer 1 ----------------
__global__ __launch_bounds__(256) void k_gemm1(const float* __restrict__ x, const float* __restrict__ W1,
                                               float* __restrict__ xl1){
    __shared__ float xs[8][FEAT];
    int r0 = blockIdx.x * 8;
    for (int r = 0; r < 8; ++r)
        for (int c = threadIdx.x; c < FEAT; c += 256)
            xs[r][c] = x[(r0 + r)*FEAT + c];
    __syncthreads();
    for (int j = threadIdx.x; j < D1; j += 256){
        float acc[8];
#pragma unroll
        for (int r = 0; r < 8; ++r) acc[r] = 0.f;
        for (int k = 0; k < FEAT; ++k){
            float w = W1[k*D1 + j];
#pragma unroll
            for (int r = 0; r < 8; ++r) acc[r] += xs[r][k] * w;
        }
#pragma unroll
        for (int r = 0; r < 8; ++r) xl1[(size_t)(r0 + r)*D1 + j] = acc[r];
    }
}

__global__ __launch_bounds__(256) void k_alpha1(const float* __restrict__ xl1, const float* __restrict__ asw,
                                                const float* __restrict__ adw,
                                                float* __restrict__ as1, float* __restrict__ ad1){
    __shared__ float sa[HEADS*FEAT], sd[HEADS*FEAT];
    for (int i = threadIdx.x; i < HEADS*FEAT; i += 256){ sa[i] = asw[i]; sd[i] = adw[i]; }
    __syncthreads();
    int gid = blockIdx.x*256 + threadIdx.x;
    if (gid >= NN*HEADS) return;
    int n = gid / HEADS, h = gid % HEADS;
    const float* row = xl1 + (size_t)n*D1 + h*FEAT;
    const float* wa = sa + h*FEAT; const float* wd = sd + h*FEAT;
    float a = 0.f, d = 0.f;
    for (int c = 0; c < FEAT; ++c){ float v = row[c]; a += v*wa[c]; d += v*wd[c]; }
    as1[gid] = a; ad1[gid] = d;
}

__global__ __launch_bounds__(64) void k_gat1(const float* __restrict__ xl1, const float* __restrict__ as1,
                                             const float* __restrict__ ad1, const int* __restrict__ off,
                                             const int* __restrict__ csrc, const float* __restrict__ b1,
                                             float* __restrict__ h1){
    int dst = blockIdx.x, lane = threadIdx.x;
    int beg = off[dst], end = off[dst + 1];
    __shared__ float adh[HEADS];
    __shared__ float al[64*HEADS];
    if (lane < HEADS) adh[lane] = ad1[dst*HEADS + lane];
    __syncthreads();
    float m[HEADS], sm[HEADS];
#pragma unroll
    for (int h = 0; h < HEADS; ++h){ m[h] = -1e30f; sm[h] = 0.f; }
    for (int e = beg + lane; e < end; e += 64){
        int s = csrc[e];
#pragma unroll
        for (int h = 0; h < HEADS; ++h){
            float v = as1[s*HEADS + h] + adh[h];
            v = v > 0.f ? v : SLOPE*v;
            m[h] = fmaxf(m[h], v);
        }
    }
#pragma unroll
    for (int h = 0; h < HEADS; ++h)
        for (int o = 32; o; o >>= 1) m[h] = fmaxf(m[h], __shfl_xor(m[h], o));
    for (int e = beg + lane; e < end; e += 64){
        int s = csrc[e];
#pragma unroll
        for (int h = 0; h < HEADS; ++h){
            float v = as1[s*HEADS + h] + adh[h];
            v = v > 0.f ? v : SLOPE*v;
            sm[h] += __expf(v - m[h]);
        }
    }
#pragma unroll
    for (int h = 0; h < HEADS; ++h){
        for (int o = 32; o; o >>= 1) sm[h] += __shfl_xor(sm[h], o);
        sm[h] = 1.f / (sm[h] + 1e-16f);
    }
    int hidx[13];
#pragma unroll
    for (int i = 0; i < 13; ++i){ int c = lane + (i << 6); hidx[i] = (c < D1) ? (c / FEAT) : 0; }
    float acc[13];
#pragma unroll
    for (int i = 0; i < 13; ++i) acc[i] = 0.f;
    for (int base = beg; base < end; base += 64){
        int cnt = min(64, end - base);
        __syncthreads();
        for (int idx = lane; idx < cnt*HEADS; idx += 64){
            int e = base + idx / HEADS, h = idx % HEADS;
            int s = csrc[e];
            float v = as1[s*HEADS + h] + adh[h];
            v = v > 0.f ? v : SLOPE*v;
            al[idx] = __expf(v - m[h]) * sm[h];
        }
        __syncthreads();
        for (int q = 0; q < cnt; ++q){
            const float* row = xl1 + (size_t)csrc[base + q]*D1;
            const float* alq = al + q*HEADS;
#pragma unroll
            for (int i = 0; i < 12; ++i) acc[i] += alq[hidx[i]] * row[lane + (i << 6)];
            if (lane < 12) acc[12] += alq[hidx[12]] * row[lane + 768];
        }
    }
#pragma unroll
    for (int i = 0; i < 13; ++i){
        int c = lane + (i << 6);
        if (c < D1){
            float v = acc[i] + b1[c];
            v = v > 0.f ? v : __expf(v) - 1.f;   // ELU
            h1[(size_t)dst*D1 + c] = v;
        }
    }
}

// ---------------- GAT layer 2 ----------------
__global__ __launch_bounds__(128) void k_gemm2(const float* __restrict__ h1, const float* __restrict__ W2,
                                               float* __restrict__ xl2){
    __shared__ float hs[8][D1];
    int r0 = blockIdx.x * 8;
    for (int r = 0; r < 8; ++r)
        for (int c = threadIdx.x; c < D1; c += 128)
            hs[r][c] = h1[(size_t)(r0 + r)*D1 + c];
    __syncthreads();
    int j = threadIdx.x;
    float acc[8];
#pragma unroll
    for (int r = 0; r < 8; ++r) acc[r] = 0.f;
    for (int k = 0; k < D1; ++k){
        float w = W2[k*OD + j];
#pragma unroll
        for (int r = 0; r < 8; ++r) acc[r] += hs[r][k] * w;
    }
#pragma unroll
    for (int r = 0; r < 8; ++r) xl2[(size_t)(r0 + r)*OD + j] = acc[r];
}

__global__ __launch_bounds__(64) void k_alpha2(const float* __restrict__ xl2, const float* __restrict__ s2w,
                                               const float* __restrict__ d2w,
                                               float* __restrict__ as2, float* __restrict__ ad2){
    int n = blockIdx.x, lane = threadIdx.x;
    float v0 = xl2[(size_t)n*OD + lane], v1 = xl2[(size_t)n*OD + 64 + lane];
    float a = v0*s2w[lane] + v1*s2w[64 + lane];
    float d = v0*d2w[lane] + v1*d2w[64 + lane];
    for (int o = 32; o; o >>= 1){ a += __shfl_xor(a, o); d += __shfl_xor(d, o); }
    if (lane == 0){ as2[n] = a; ad2[n] = d; }
}

__global__ __launch_bounds__(64) void k_gat2(const float* __restrict__ xl2, const float* __restrict__ as2,
                                             const float* __restrict__ ad2, const int* __restrict__ off,
                                             const int* __restrict__ csrc, const float* __restrict__ b2,
                                             float* __restrict__ h2){
    int dst = blockIdx.x, lane = threadIdx.x;
    int beg = off[dst], end = off[dst + 1];
    float ad = ad2[dst];
    float m = -1e30f, sm = 0.f;
    for (int e = beg + lane; e < end; e += 64){
        float v = as2[csrc[e]] + ad; v = v > 0.f ? v : SLOPE*v;
        m = fmaxf(m, v);
    }
    for (int o = 32; o; o >>= 1) m = fmaxf(m, __shfl_xor(m, o));
    for (int e = beg + lane; e < end; e += 64){
        float v = as2[csrc[e]] + ad; v = v > 0.f ? v : SLOPE*v;
        sm += __expf(v - m);
    }
    for (int o = 32; o; o >>= 1) sm += __shfl_xor(sm, o);
    float inv = 1.f / (sm + 1e-16f);
    float a0 = 0.f, a1 = 0.f;
    for (int e = beg; e < end; ++e){
        int s = csrc[e];
        float v = as2[s] + ad; v = v > 0.f ? v : SLOPE*v;
        float alw = __expf(v - m) * inv;
        a0 += alw * xl2[(size_t)s*OD + lane];
        a1 += alw * xl2[(size_t)s*OD + 64 + lane];
    }
    float o0 = a0 + b2[lane];      o0 = o0 > 0.f ? o0 : 0.f;
    float o1 = a1 + b2[64 + lane]; o1 = o1 > 0.f ? o1 : 0.f;
    h2[(size_t)dst*OD + lane] = o0;
    h2[(size_t)dst*OD + 64 + lane] = o1;
}

// ---------------- pooling + graph FC ----------------
__global__ __launch_bounds__(128) void k_pool(const float* __restrict__ h2, const int* __restrict__ batch,
                                              float* __restrict__ g){
    int b = blockIdx.x, t = threadIdx.x;
    int lo = 0, hi = NN;
    while (lo < hi){ int mid = (lo + hi) >> 1; if (batch[mid] < b) lo = mid + 1; else hi = mid; }
    int s0 = lo;
    lo = s0; hi = NN;
    while (lo < hi){ int mid = (lo + hi) >> 1; if (batch[mid] < b + 1) lo = mid + 1; else hi = mid; }
    int s1 = lo;
    float mx = 0.f;
    for (int n = s0; n < s1; ++n) mx = fmaxf(mx, h2[(size_t)n*OD + t]);
    g[b*OD + t] = mx;
}

__global__ __launch_bounds__(128) void k_fcg(const float* __restrict__ g, const float* __restrict__ w,
                                             const float* __restrict__ bias, float* __restrict__ gfc){
    __shared__ float row[OD];
    int b = blockIdx.x, j = threadIdx.x;
    row[j] = g[b*OD + j];
    __syncthreads();
    float acc = 0.f;
    for (int k = 0; k < OD; ++k) acc += row[k] * w[k*OD + j];
    acc += bias[j];
    gfc[b*OD + j] = acc > 0.f ? acc : 0.f;
}

// ---------------- protein branch (A-bucket conv + fc_xt, fused per b) ----------------
__global__ __launch_bounds__(256) void k_prot(const int* __restrict__ target, const float* __restrict__ emb,
                                              const float* __restrict__ convw, const float* __restrict__ convb,
                                              const float* __restrict__ fxw, const float* __restrict__ fxb,
                                              float* __restrict__ xt){
    __shared__ float A[256*VOC];           // [o*8+k][v]
    __shared__ float embs[VOC*128 + 16];   // padded tail
    __shared__ float cs[32*121];
    __shared__ int   ts[PL];
    __shared__ float part[256];
    int b = blockIdx.x, t = threadIdx.x;
    for (int i = t; i < PL; i += 256) ts[i] = target[b*PL + i];
    for (int i = t; i < VOC*128; i += 256) embs[i] = emb[i];
    if (t < 16) embs[VOC*128 + t] = 0.f;
#pragma unroll
    for (int i = 0; i < VOC; ++i) A[t*VOC + i] = 0.f;
    __syncthreads();
    {   // phase 1: A[o,k,v] = sum over positions i with token v of w[o,i,k]
        int o = t >> 3, k = t & 7;
        const float* wp = convw + (size_t)o*PL*8 + k;
        float* Ar = A + t*VOC;
        for (int i = 0; i < PL; ++i)
            Ar[ts[i]] += wp[i*8];
    }
    __syncthreads();
    {   // phase 2: c[o,p] = relu( sum_v sum_k A[o,k,v]*emb[v,p+k] + cb[o] )
        int o2 = t >> 3, pg = t & 7;
        int p0 = pg * 16;
        float accp[16];
#pragma unroll
        for (int i = 0; i < 16; ++i) accp[i] = 0.f;
        const float* Ao = A + (o2*8)*VOC;
        for (int v = 0; v < VOC; ++v){
            float w[24];
            const float* er = embs + v*128 + p0;
#pragma unroll
            for (int i = 0; i < 24; ++i) w[i] = er[i];
#pragma unroll
            for (int k2 = 0; k2 < 8; ++k2){
                float a = Ao[k2*VOC + v];
#pragma unroll
                for (int j = 0; j < 16; ++j) accp[j] += a * w[j + k2];
            }
        }
        float cb = convb[o2];
#pragma unroll
        for (int j = 0; j < 16; ++j){
            int p = p0 + j;
            if (p < 121){
                float v2 = accp[j] + cb;
                cs[o2*121 + p] = v2 > 0.f ? v2 : 0.f;
            }
        }
    }
    __syncthreads();
    {   // phase 3: xt[b,:] = cs @ fc_xt_w + fc_xt_b
        int j = t & 127, hf = t >> 7;
        const float* wcol = fxw + j;
        float acc = 0.f;
        for (int op = hf*1936; op < (hf + 1)*1936; ++op)
            acc += cs[op] * wcol[(size_t)op*128];
        part[t] = acc;
    }
    __syncthreads();
    if (t < 128)
        xt[b*OD + t] = part[t] + part[t + 128] + fxb[t];
}

// ---------------- fused head ----------------
__global__ __launch_bounds__(256) void k_fc1(const float* __restrict__ gfc, const float* __restrict__ xt,
                                             const float* __restrict__ w, const float* __restrict__ bias,
                                             float* __restrict__ out){
    __shared__ float xc[256];
    int b = blockIdx.x, t = threadIdx.x;
    xc[t] = (t < 128) ? gfc[b*OD + t] : xt[b*OD + t - 128];
    __syncthreads();
#pragma unroll
    for (int rep = 0; rep < 4; ++rep){
        int j = t + rep*256;
        float acc = 0.f;
        for (int k = 0; k < 256; ++k) acc += xc[k] * w[(size_t)k*1024 + j];
        acc += bias[j];
        out[b*1024 + j] = acc > 0.f ? acc : 0.f;
    }
}

__global__ __launch_bounds__(256) void k_fc2(const float* __restrict__ in, const float* __restrict__ w,
                                             const float* __restrict__ bias, float* __restrict__ out){
    __shared__ float row[1024];
    int b = blockIdx.x, t = threadIdx.x;
    for (int i = t; i < 1024; i += 256) row[i] = in[b*1024 + i];
    __syncthreads();
    float acc = 0.f;
    for (int k = 0; k < 1024; ++k) acc += row[k] * w[(size_t)k*256 + t];
    acc += bias[t];
    out[b*256 + t] = acc > 0.f ? acc : 0.f;
}

__global__ __launch_bounds__(64) void k_out(const float* __restrict__ in, const float* __restrict__ w,
                                            const float* __restrict__ bias, float* __restrict__ out){
    int b = blockIdx.x, lane = threadIdx.x;
    float acc = 0.f;
#pragma unroll
    for (int r = 0; r < 4; ++r){ int k = lane + r*64; acc += in[b*256 + k] * w[k]; }
    for (int o = 32; o; o >>= 1) acc += __shfl_xor(acc, o);
    if (lane == 0) out[b] = acc + bias[0];   // f32 output (reference dtype)
}

extern "C" void kernel_launch(void* const* d_in, const int* in_sizes, int n_in,
                              void* d_out, int out_size, void* d_ws, size_t ws_size,
                              hipStream_t stream){
    const float* x    = (const float*)d_in[0];
    const int*  ei    = (const int*)d_in[1];
    const int*  batch = (const int*)d_in[2];
    const int*  target= (const int*)d_in[3];
    const float* W1   = (const float*)d_in[4];
    const float* as1w = (const float*)d_in[5];
    const float* ad1w = (const float*)d_in[6];
    const float* b1   = (const float*)d_in[7];
    const float* W2   = (const float*)d_in[8];
    const float* as2w = (const float*)d_in[9];
    const float* ad2w = (const float*)d_in[10];
    const float* b2   = (const float*)d_in[11];
    const float* fgw  = (const float*)d_in[12];
    const float* fgb  = (const float*)d_in[13];
    const float* emb  = (const float*)d_in[14];
    const float* cw   = (const float*)d_in[15];
    const float* cb   = (const float*)d_in[16];
    const float* fxw  = (const float*)d_in[17];
    const float* fxb  = (const float*)d_in[18];
    const float* f1w  = (const float*)d_in[19];
    const float* f1b  = (const float*)d_in[20];
    const float* f2w  = (const float*)d_in[21];
    const float* f2b  = (const float*)d_in[22];
    const float* ow   = (const float*)d_in[23];
    const float* ob   = (const float*)d_in[24];

    float* f = (float*)d_ws;
    size_t o = 0;
    float* xl1 = f + o; o += (size_t)NN*D1;
    float* h1  = f + o; o += (size_t)NN*D1;
    float* as1 = f + o; o += (size_t)NN*HEADS;
    float* ad1 = f + o; o += (size_t)NN*HEADS;
    float* xl2 = f + o; o += (size_t)NN*OD;
    float* h2  = f + o; o += (size_t)NN*OD;
    float* as2 = f + o; o += NN;
    float* ad2 = f + o; o += NN;
    float* g   = f + o; o += NB*OD;
    float* gfc = f + o; o += NB*OD;
    float* xt  = f + o; o += NB*OD;
    float* hf1 = f + o; o += NB*1024;
    float* hf2 = f + o; o += NB*256;
    int* cnt   = (int*)(f + o); o += NN;
    int* off   = (int*)(f + o); o += NN + 1;
    int* csrc  = (int*)(f + o); o += ET;
    (void)ws_size; (void)in_sizes; (void)n_in; (void)out_size;

    // CSR by destination
    hipMemsetAsync(cnt, 0, NN*sizeof(int), stream);
    k_hist<<<(ET + 255)/256, 256, 0, stream>>>(ei, cnt);
    k_scan<<<1, 1024, 0, stream>>>(cnt, off);
    hipMemsetAsync(cnt, 0, NN*sizeof(int), stream);
    k_fill<<<(ET + 255)/256, 256, 0, stream>>>(ei, off, cnt, csrc);

    // GAT layer 1
    k_gemm1<<<NN/8, 256, 0, stream>>>(x, W1, xl1);
    k_alpha1<<<(NN*HEADS)/256, 256, 0, stream>>>(xl1, as1w, ad1w, as1, ad1);
    k_gat1<<<NN, 64, 0, stream>>>(xl1, as1, ad1, off, csrc, b1, h1);

    // GAT layer 2
    k_gemm2<<<NN/8, 128, 0, stream>>>(h1, W2, xl2);
    k_alpha2<<<NN, 64, 0, stream>>>(xl2, as2w, ad2w, as2, ad2);
    k_gat2<<<NN, 64, 0, stream>>>(xl2, as2, ad2, off, csrc, b2, h2);

    // pooling + graph fc
    k_pool<<<NB, 128, 0, stream>>>(h2, batch, g);
    k_fcg<<<NB, 128, 0, stream>>>(g, fgw, fgb, gfc);

    // protein branch
    k_prot<<<NB, 256, 0, stream>>>(target, emb, cw, cb, fxw, fxb, xt);

    // head
    k_fc1<<<NB, 256, 0, stream>>>(gfc, xt, f1w, f1b, hf1);
    k_fc2<<<NB, 256, 0, stream>>>(hf1, f2w, f2b, hf2);
    k_out<<<NB, 64, 0, stream>>>(hf2, ow, ob, (float*)d_out);
}

// Round 4
// 526.003 us; speedup vs baseline: 1.2064x; 1.2064x over previous
//
#include <hip/hip_runtime.h>
#include <hip/hip_bf16.h>

using bf16 = __hip_bfloat16;

#define NN 16384
#define NE 262144
#define ET (NE + NN)
#define NB 128
#define FEAT 78
#define HEADS 10
#define D1 780
#define OD 128
#define PL 1000
#define VOC 26
#define SLOPE 0.2f

// ---------------- CSR build ----------------
__global__ void k_hist(const int* __restrict__ ei, int* __restrict__ cnt){
    int e = blockIdx.x*256 + threadIdx.x;
    if (e >= ET) return;
    int dst = (e < NE) ? ei[NE + e] : (e - NE);
    atomicAdd(&cnt[dst], 1);
}

__global__ __launch_bounds__(1024) void k_scan(const int* __restrict__ cnt, int* __restrict__ off){
    __shared__ int ps[1024];
    int t = threadIdx.x;
    int loc[16]; int s = 0;
#pragma unroll
    for (int j = 0; j < 16; ++j){ loc[j] = cnt[t*16 + j]; s += loc[j]; }
    ps[t] = s; __syncthreads();
    for (int d = 1; d < 1024; d <<= 1){
        int v = (t >= d) ? ps[t - d] : 0;
        __syncthreads();
        ps[t] += v;
        __syncthreads();
    }
    int run = (t == 0) ? 0 : ps[t - 1];
#pragma unroll
    for (int j = 0; j < 16; ++j){ off[t*16 + j] = run; run += loc[j]; }
    if (t == 1023) off[NN] = run;
}

__global__ void k_fill(const int* __restrict__ ei, const int* __restrict__ off,
                       int* __restrict__ cur, int* __restrict__ csrc){
    int e = blockIdx.x*256 + threadIdx.x;
    if (e >= ET) return;
    int src, dst;
    if (e < NE){ src = ei[e]; dst = ei[NE + e]; } else { src = e - NE; dst = src; }
    int p = off[dst] + atomicAdd(&cur[dst], 1);
    csrc[p] = src;
}

// ---------------- GAT layer 1 (x-space) ----------------
// va_s[h][k] = sum_j W1[k][h*78+j] * asw[h][j]  (and same for va_d)
__global__ __launch_bounds__(256) void k_va(const float* __restrict__ W1, const float* __restrict__ asw,
                                            const float* __restrict__ adw,
                                            float* __restrict__ vas, float* __restrict__ vad){
    __shared__ float sa[D1], sd[D1];
    int t = threadIdx.x;
    for (int i = t; i < D1; i += 256){ sa[i] = asw[i]; sd[i] = adw[i]; }
    __syncthreads();
    for (int idx = t; idx < D1; idx += 256){
        int h = idx / FEAT, k = idx % FEAT;
        const float* wr = W1 + (size_t)k*D1 + h*FEAT;
        float a = 0.f, d = 0.f;
        for (int j = 0; j < FEAT; ++j){ float w = wr[j]; a += w*sa[h*FEAT + j]; d += w*sd[h*FEAT + j]; }
        vas[idx] = a; vad[idx] = d;
    }
}

// as1[n][h] = x[n] . vas[h],  ad1 similarly
__global__ __launch_bounds__(256) void k_alpha1x(const float* __restrict__ x, const float* __restrict__ vas,
                                                 const float* __restrict__ vad,
                                                 float* __restrict__ as1, float* __restrict__ ad1){
    __shared__ float xs[64*79];
    __shared__ float va[D1], vd[D1];
    int n0 = blockIdx.x * 64, t = threadIdx.x;
    for (int i = t; i < D1; i += 256){ va[i] = vas[i]; vd[i] = vad[i]; }
    for (int i = t; i < 64*FEAT; i += 256){
        int n = i / FEAT, k = i % FEAT;
        xs[n*79 + k] = x[(size_t)n0*FEAT + i];
    }
    __syncthreads();
    for (int p = t; p < 64*HEADS; p += 256){
        int h = p >> 6, nl = p & 63;
        const float* xr = xs + nl*79;
        const float* pa = va + h*FEAT; const float* pd = vd + h*FEAT;
        float a = 0.f, d = 0.f;
        for (int k = 0; k < FEAT; ++k){ float xv = xr[k]; a += xv*pa[k]; d += xv*pd[k]; }
        as1[(size_t)(n0 + nl)*HEADS + h] = a;
        ad1[(size_t)(n0 + nl)*HEADS + h] = d;
    }
}

// per dst: online softmax (10 lanes) + x-space aggregation (lane-per-column)
__global__ __launch_bounds__(64) void k_gat1x(const float* __restrict__ x, const float* __restrict__ as1,
                                              const float* __restrict__ ad1, const int* __restrict__ off,
                                              const int* __restrict__ csrc,
                                              float* __restrict__ agg){
    __shared__ float mh_l[HEADS], sv_l[HEADS];
    int dst = blockIdx.x, lane = threadIdx.x;
    int beg = off[dst], end = off[dst + 1];
    if (lane < HEADS){
        float adv = ad1[(size_t)dst*HEADS + lane];
        float m = -1e30f, sm = 0.f;
        for (int e = beg; e < end; ++e){
            int s = csrc[e];
            float v = as1[(size_t)s*HEADS + lane] + adv;
            v = v > 0.f ? v : SLOPE*v;
            float mn = fmaxf(m, v);
            sm = sm*__expf(m - mn) + __expf(v - mn);
            m = mn;
        }
        mh_l[lane] = m;
        sv_l[lane] = 1.f/(sm + 1e-16f);
    }
    __syncthreads();
    float mh[HEADS], sv[HEADS], adh[HEADS];
#pragma unroll
    for (int h = 0; h < HEADS; ++h){
        mh[h] = mh_l[h]; sv[h] = sv_l[h];
        adh[h] = ad1[(size_t)dst*HEADS + h];
    }
    float acc1[HEADS], acc2[HEADS];
#pragma unroll
    for (int h = 0; h < HEADS; ++h){ acc1[h] = 0.f; acc2[h] = 0.f; }
    for (int e = beg; e < end; ++e){
        int s = csrc[e];
        const float* xr = x + (size_t)s*FEAT;
        float xv1 = xr[lane];
        float xv2 = (lane < FEAT - 64) ? xr[64 + lane] : 0.f;
        float vv[HEADS];
#pragma unroll
        for (int h = 0; h < HEADS; ++h) vv[h] = as1[(size_t)s*HEADS + h];
#pragma unroll
        for (int h = 0; h < HEADS; ++h){
            float v = vv[h] + adh[h];
            v = v > 0.f ? v : SLOPE*v;
            float al = __expf(v - mh[h]) * sv[h];
            acc1[h] += al*xv1;
            acc2[h] += al*xv2;
        }
    }
#pragma unroll
    for (int h = 0; h < HEADS; ++h)
        agg[(size_t)dst*D1 + h*FEAT + lane] = acc1[h];
    if (lane < FEAT - 64){
#pragma unroll
        for (int h = 0; h < HEADS; ++h)
            agg[(size_t)dst*D1 + h*FEAT + 64 + lane] = acc2[h];
    }
}

// h1[n][c] = ELU( sum_k agg[n][h*78+k] * W1[k][c] + b1[c] ),  h = c/78 (block-diagonal)
__global__ __launch_bounds__(320) void k_post1(const float* __restrict__ agg, const float* __restrict__ W1,
                                               const float* __restrict__ b1, float* __restrict__ h1){
    __shared__ __align__(16) float ags[8][800];
    int r0 = blockIdx.x * 8, t = threadIdx.x;
    for (int i = t; i < 8*D1; i += 320){
        int r = i / D1, c = i % D1, h = c / FEAT, j = c % FEAT;
        ags[r][h*80 + j] = agg[(size_t)(r0 + r)*D1 + c];
    }
    __syncthreads();
    if (t < 260){
        int h = t / 26, jj = (t % 26)*3;
        int cb = h*FEAT + jj;
        const float* wcol = W1 + cb;
        float acc[8][3];
#pragma unroll
        for (int r = 0; r < 8; ++r){ acc[r][0] = 0.f; acc[r][1] = 0.f; acc[r][2] = 0.f; }
        int k = 0;
        for (; k + 4 <= FEAT; k += 4){
            float4 a[8];
#pragma unroll
            for (int r = 0; r < 8; ++r) a[r] = *(const float4*)&ags[r][h*80 + k];
#pragma unroll
            for (int kk = 0; kk < 4; ++kk){
                const float* wr = wcol + (size_t)(k + kk)*D1;
                float w0 = wr[0], w1 = wr[1], w2 = wr[2];
#pragma unroll
                for (int r = 0; r < 8; ++r){
                    float av = ((const float*)&a[r])[kk];
                    acc[r][0] += av*w0; acc[r][1] += av*w1; acc[r][2] += av*w2;
                }
            }
        }
        for (; k < FEAT; ++k){
            const float* wr = wcol + (size_t)k*D1;
            float w0 = wr[0], w1 = wr[1], w2 = wr[2];
#pragma unroll
            for (int r = 0; r < 8; ++r){
                float av = ags[r][h*80 + k];
                acc[r][0] += av*w0; acc[r][1] += av*w1; acc[r][2] += av*w2;
            }
        }
        float bv0 = b1[cb], bv1 = b1[cb+1], bv2 = b1[cb+2];
#pragma unroll
        for (int r = 0; r < 8; ++r){
            float v0 = acc[r][0] + bv0, v1 = acc[r][1] + bv1, v2 = acc[r][2] + bv2;
            v0 = v0 > 0.f ? v0 : __expf(v0) - 1.f;
            v1 = v1 > 0.f ? v1 : __expf(v1) - 1.f;
            v2 = v2 > 0.f ? v2 : __expf(v2) - 1.f;
            size_t base = (size_t)(r0 + r)*D1 + cb;
            h1[base] = v0; h1[base+1] = v1; h1[base+2] = v2;
        }
    }
}

// ---------------- GAT layer 2 ----------------
#define KC 39
__global__ __launch_bounds__(256) void k_gemm2(const float* __restrict__ h1, const float* __restrict__ W2,
                                               float* __restrict__ xl2){
    __shared__ __align__(16) float as[KC][36];
    __shared__ __align__(16) float ws[KC][128];
    int r0 = blockIdx.x * 32, t = threadIdx.x;
    int rg = t >> 5, jq = t & 31;
    float acc[4][4];
#pragma unroll
    for (int i = 0; i < 4; ++i)
#pragma unroll
        for (int j = 0; j < 4; ++j) acc[i][j] = 0.f;
    for (int kc = 0; kc < D1; kc += KC){
        for (int i = t; i < 32*KC; i += 256){
            int r = i / KC, k = i % KC;
            as[k][r] = h1[(size_t)(r0 + r)*D1 + kc + k];
        }
        for (int i = t; i < KC*128; i += 256){
            int k = i >> 7, j = i & 127;
            ws[k][j] = W2[(size_t)(kc + k)*OD + j];
        }
        __syncthreads();
        for (int k = 0; k < KC; ++k){
            float4 a4 = *(const float4*)&as[k][rg*4];
            float4 w4 = *(const float4*)&ws[k][jq*4];
            float av[4] = {a4.x, a4.y, a4.z, a4.w};
            float wv[4] = {w4.x, w4.y, w4.z, w4.w};
#pragma unroll
            for (int i = 0; i < 4; ++i)
#pragma unroll
                for (int j = 0; j < 4; ++j) acc[i][j] += av[i]*wv[j];
        }
        __syncthreads();
    }
#pragma unroll
    for (int i = 0; i < 4; ++i){
        float4 o4 = make_float4(acc[i][0], acc[i][1], acc[i][2], acc[i][3]);
        *(float4*)&xl2[(size_t)(r0 + rg*4 + i)*OD + jq*4] = o4;
    }
}

__global__ __launch_bounds__(64) void k_alpha2(const float* __restrict__ xl2, const float* __restrict__ s2w,
                                               const float* __restrict__ d2w,
                                               float* __restrict__ as2, float* __restrict__ ad2){
    int n = blockIdx.x, lane = threadIdx.x;
    float v0 = xl2[(size_t)n*OD + lane], v1 = xl2[(size_t)n*OD + 64 + lane];
    float a = v0*s2w[lane] + v1*s2w[64 + lane];
    float d = v0*d2w[lane] + v1*d2w[64 + lane];
    for (int o = 32; o; o >>= 1){ a += __shfl_xor(a, o); d += __shfl_xor(d, o); }
    if (lane == 0){ as2[n] = a; ad2[n] = d; }
}

__global__ __launch_bounds__(64) void k_gat2(const float* __restrict__ xl2, const float* __restrict__ as2,
                                             const float* __restrict__ ad2, const int* __restrict__ off,
                                             const int* __restrict__ csrc, const float* __restrict__ b2,
                                             float* __restrict__ h2){
    int dst = blockIdx.x, lane = threadIdx.x;
    int beg = off[dst], end = off[dst + 1];
    float ad = ad2[dst];
    float m = -1e30f, sm = 0.f;
    for (int e = beg + lane; e < end; e += 64){
        float v = as2[csrc[e]] + ad; v = v > 0.f ? v : SLOPE*v;
        m = fmaxf(m, v);
    }
    for (int o = 32; o; o >>= 1) m = fmaxf(m, __shfl_xor(m, o));
    for (int e = beg + lane; e < end; e += 64){
        float v = as2[csrc[e]] + ad; v = v > 0.f ? v : SLOPE*v;
        sm += __expf(v - m);
    }
    for (int o = 32; o; o >>= 1) sm += __shfl_xor(sm, o);
    float inv = 1.f / (sm + 1e-16f);
    float a0 = 0.f, a1 = 0.f;
    for (int e = beg; e < end; ++e){
        int s = csrc[e];
        float v = as2[s] + ad; v = v > 0.f ? v : SLOPE*v;
        float alw = __expf(v - m) * inv;
        a0 += alw * xl2[(size_t)s*OD + lane];
        a1 += alw * xl2[(size_t)s*OD + 64 + lane];
    }
    float o0 = a0 + b2[lane];      o0 = o0 > 0.f ? o0 : 0.f;
    float o1 = a1 + b2[64 + lane]; o1 = o1 > 0.f ? o1 : 0.f;
    h2[(size_t)dst*OD + lane] = o0;
    h2[(size_t)dst*OD + 64 + lane] = o1;
}

// ---------------- pooling + graph FC ----------------
__global__ __launch_bounds__(128) void k_pool(const float* __restrict__ h2, const int* __restrict__ batch,
                                              float* __restrict__ g){
    int b = blockIdx.x, t = threadIdx.x;
    int lo = 0, hi = NN;
    while (lo < hi){ int mid = (lo + hi) >> 1; if (batch[mid] < b) lo = mid + 1; else hi = mid; }
    int s0 = lo;
    lo = s0; hi = NN;
    while (lo < hi){ int mid = (lo + hi) >> 1; if (batch[mid] < b + 1) lo = mid + 1; else hi = mid; }
    int s1 = lo;
    float mx = 0.f;
    for (int n = s0; n < s1; ++n) mx = fmaxf(mx, h2[(size_t)n*OD + t]);
    g[b*OD + t] = mx;
}

__global__ __launch_bounds__(128) void k_fcg(const float* __restrict__ g, const float* __restrict__ w,
                                             const float* __restrict__ bias, float* __restrict__ gfc){
    __shared__ float row[OD];
    int b = blockIdx.x, j = threadIdx.x;
    row[j] = g[b*OD + j];
    __syncthreads();
    float acc = 0.f;
    for (int k = 0; k < OD; ++k) acc += row[k] * w[k*OD + j];
    acc += bias[j];
    gfc[b*OD + j] = acc > 0.f ? acc : 0.f;
}

// ---------------- protein branch ----------------
// block = (b, half): half selects 16 output channels. Deterministic stable
// counting-sort of positions by token (ballot), register bucket accumulation.
__global__ __launch_bounds__(256) void k_prot(const int* __restrict__ target, const float* __restrict__ emb,
                                              const float* __restrict__ convw, const float* __restrict__ convb,
                                              const float* __restrict__ fxw, float* __restrict__ xtp){
    __shared__ int   ts[PL];
    __shared__ int   sorted[2][500];
    __shared__ int   offs[2][27];
    __shared__ float A0[128][27];
    __shared__ float A1[128][27];
    __shared__ float embs[VOC*128 + 16];
    __shared__ float cs[16][121];
    __shared__ float part[256];
    int b = blockIdx.x >> 1, half = blockIdx.x & 1;
    int t = threadIdx.x;
    for (int i = t; i < PL; i += 256) ts[i] = target[b*PL + i];
    for (int i = t; i < VOC*128; i += 256) embs[i] = emb[i];
    if (t < 16) embs[VOC*128 + t] = 0.f;
    __syncthreads();
    int wv = t >> 6, lane = t & 63;
    if (wv < 2){
        int base = wv * 500;
        int cnts[26];
#pragma unroll
        for (int v = 0; v < 26; ++v) cnts[v] = 0;
        for (int r = 0; r < 8; ++r){
            int idx = r*64 + lane;
            int v = (idx < 500) ? ts[base + idx] : -1;
#pragma unroll
            for (int vv = 0; vv < 26; ++vv)
                cnts[vv] += __popcll(__ballot(v == vv));
        }
        int pre[27]; pre[0] = 0;
#pragma unroll
        for (int v = 0; v < 26; ++v) pre[v+1] = pre[v] + cnts[v];
        if (lane == 0){
#pragma unroll
            for (int v = 0; v < 27; ++v) offs[wv][v] = pre[v];
        }
        int run[26];
#pragma unroll
        for (int v = 0; v < 26; ++v) run[v] = pre[v];
        unsigned long long below = (1ull << lane) - 1ull;
        for (int r = 0; r < 8; ++r){
            int idx = r*64 + lane;
            int v = (idx < 500) ? ts[base + idx] : -1;
#pragma unroll
            for (int vv = 0; vv < 26; ++vv){
                unsigned long long m = __ballot(v == vv);
                if (v == vv) sorted[wv][run[vv] + __popcll(m & below)] = base + idx;
                run[vv] += __popcll(m);
            }
        }
    }
    __syncthreads();
    {   // phase 1: bucket-register accumulation of A[o,k,v]
        int hp = t >> 7;
        int pair = t & 127;
        int o = half*16 + (pair >> 3), k = pair & 7;
        const float* wp = convw + (size_t)o*PL*8 + k;
        float (*Ax)[27] = hp ? A1 : A0;
        for (int v = 0; v < 26; ++v){
            float a = 0.f;
            int e0 = offs[hp][v], e1 = offs[hp][v+1];
            for (int e = e0; e < e1; ++e) a += wp[(size_t)sorted[hp][e]*8];
            Ax[pair][v] = a;
        }
    }
    __syncthreads();
    {   // phase 2: c[o,p] = relu( sum_v sum_k A[o,k,v]*emb[v,p+k] + cb )
        int o_l = t >> 4, pg = t & 15, p0 = pg * 8;
        float accp[8];
#pragma unroll
        for (int i = 0; i < 8; ++i) accp[i] = 0.f;
        int rb = o_l*8;
        for (int v = 0; v < 26; ++v){
            float w[15];
#pragma unroll
            for (int i = 0; i < 15; ++i) w[i] = embs[v*128 + p0 + i];
#pragma unroll
            for (int k2 = 0; k2 < 8; ++k2){
                float a = A0[rb + k2][v] + A1[rb + k2][v];
#pragma unroll
                for (int j = 0; j < 8; ++j) accp[j] += a * w[j + k2];
            }
        }
        float cbv = convb[half*16 + o_l];
#pragma unroll
        for (int j = 0; j < 8; ++j){
            int p = p0 + j;
            if (p < 121){
                float v2 = accp[j] + cbv;
                cs[o_l][p] = v2 > 0.f ? v2 : 0.f;
            }
        }
    }
    __syncthreads();
    {   // phase 3: partial xt over this half's 16 channels
        int j = t & 127, hf = t >> 7;
        float acc = 0.f;
        for (int ol = hf*8; ol < hf*8 + 8; ++ol){
            size_t obase = (size_t)((half*16 + ol)*121) * 128;
            for (int p = 0; p < 121; ++p)
                acc += cs[ol][p] * fxw[obase + (size_t)p*128 + j];
        }
        part[t] = acc;
    }
    __syncthreads();
    if (t < 128)
        xtp[(size_t)(b*2 + half)*128 + t] = part[t] + part[t + 128];
}

// ---------------- fused head ----------------
__global__ __launch_bounds__(256) void k_fc1(const float* __restrict__ gfc, const float* __restrict__ xtp,
                                             const float* __restrict__ fxb,
                                             const float* __restrict__ w, const float* __restrict__ bias,
                                             float* __restrict__ out){
    __shared__ float xc[256];
    int b = blockIdx.x, t = threadIdx.x;
    if (t < 128) xc[t] = gfc[b*OD + t];
    else {
        int j = t - 128;
        xc[t] = xtp[(size_t)(b*2)*128 + j] + xtp[(size_t)(b*2 + 1)*128 + j] + fxb[j];
    }
    __syncthreads();
#pragma unroll
    for (int rep = 0; rep < 4; ++rep){
        int j = t + rep*256;
        float acc = 0.f;
        for (int k = 0; k < 256; ++k) acc += xc[k] * w[(size_t)k*1024 + j];
        acc += bias[j];
        out[b*1024 + j] = acc > 0.f ? acc : 0.f;
    }
}

__global__ __launch_bounds__(256) void k_fc2(const float* __restrict__ in, const float* __restrict__ w,
                                             const float* __restrict__ bias, float* __restrict__ out){
    __shared__ float row[1024];
    int b = blockIdx.x, t = threadIdx.x;
    for (int i = t; i < 1024; i += 256) row[i] = in[b*1024 + i];
    __syncthreads();
    float acc = 0.f;
    for (int k = 0; k < 1024; ++k) acc += row[k] * w[(size_t)k*256 + t];
    acc += bias[t];
    out[b*256 + t] = acc > 0.f ? acc : 0.f;
}

__global__ __launch_bounds__(64) void k_out(const float* __restrict__ in, const float* __restrict__ w,
                                            const float* __restrict__ bias, float* __restrict__ out){
    int b = blockIdx.x, lane = threadIdx.x;
    float acc = 0.f;
#pragma unroll
    for (int r = 0; r < 4; ++r){ int k = lane + r*64; acc += in[b*256 + k] * w[k]; }
    for (int o = 32; o; o >>= 1) acc += __shfl_xor(acc, o);
    if (lane == 0) out[b] = acc + bias[0];
}

extern "C" void kernel_launch(void* const* d_in, const int* in_sizes, int n_in,
                              void* d_out, int out_size, void* d_ws, size_t ws_size,
                              hipStream_t stream){
    const float* x    = (const float*)d_in[0];
    const int*  ei    = (const int*)d_in[1];
    const int*  batch = (const int*)d_in[2];
    const int*  target= (const int*)d_in[3];
    const float* W1   = (const float*)d_in[4];
    const float* as1w = (const float*)d_in[5];
    const float* ad1w = (const float*)d_in[6];
    const float* b1   = (const float*)d_in[7];
    const float* W2   = (const float*)d_in[8];
    const float* as2w = (const float*)d_in[9];
    const float* ad2w = (const float*)d_in[10];
    const float* b2   = (const float*)d_in[11];
    const float* fgw  = (const float*)d_in[12];
    const float* fgb  = (const float*)d_in[13];
    const float* emb  = (const float*)d_in[14];
    const float* cw   = (const float*)d_in[15];
    const float* cb   = (const float*)d_in[16];
    const float* fxw  = (const float*)d_in[17];
    const float* fxb  = (const float*)d_in[18];
    const float* f1w  = (const float*)d_in[19];
    const float* f1b  = (const float*)d_in[20];
    const float* f2w  = (const float*)d_in[21];
    const float* f2b  = (const float*)d_in[22];
    const float* ow   = (const float*)d_in[23];
    const float* ob   = (const float*)d_in[24];

    float* f = (float*)d_ws;
    size_t o = 0;
    float* agg = f + o; o += (size_t)NN*D1;
    float* h1  = f + o; o += (size_t)NN*D1;
    float* as1 = f + o; o += (size_t)NN*HEADS;
    float* ad1 = f + o; o += (size_t)NN*HEADS;
    float* xl2 = f + o; o += (size_t)NN*OD;
    float* h2  = f + o; o += (size_t)NN*OD;
    float* as2 = f + o; o += NN;
    float* ad2 = f + o; o += NN;
    float* g   = f + o; o += NB*OD;
    float* gfc = f + o; o += NB*OD;
    float* xtp = f + o; o += NB*256;
    float* hf1 = f + o; o += NB*1024;
    float* hf2 = f + o; o += NB*256;
    float* vas = f + o; o += D1;
    float* vad = f + o; o += D1;
    int* cnt   = (int*)(f + o); o += NN;
    int* off   = (int*)(f + o); o += NN + 1;
    int* csrc  = (int*)(f + o); o += ET;
    (void)ws_size; (void)in_sizes; (void)n_in; (void)out_size;

    // CSR by destination
    hipMemsetAsync(cnt, 0, NN*sizeof(int), stream);
    k_hist<<<(ET + 255)/256, 256, 0, stream>>>(ei, cnt);
    k_scan<<<1, 1024, 0, stream>>>(cnt, off);
    hipMemsetAsync(cnt, 0, NN*sizeof(int), stream);
    k_fill<<<(ET + 255)/256, 256, 0, stream>>>(ei, off, cnt, csrc);

    // GAT layer 1 in x-space
    k_va<<<1, 256, 0, stream>>>(W1, as1w, ad1w, vas, vad);
    k_alpha1x<<<NN/64, 256, 0, stream>>>(x, vas, vad, as1, ad1);
    k_gat1x<<<NN, 64, 0, stream>>>(x, as1, ad1, off, csrc, agg);
    k_post1<<<NN/8, 320, 0, stream>>>(agg, W1, b1, h1);

    // GAT layer 2
    k_gemm2<<<NN/32, 256, 0, stream>>>(h1, W2, xl2);
    k_alpha2<<<NN, 64, 0, stream>>>(xl2, as2w, ad2w, as2, ad2);
    k_gat2<<<NN, 64, 0, stream>>>(xl2, as2, ad2, off, csrc, b2, h2);

    // pooling + graph fc
    k_pool<<<NB, 128, 0, stream>>>(h2, batch, g);
    k_fcg<<<NB, 128, 0, stream>>>(g, fgw, fgb, gfc);

    // protein branch
    k_prot<<<NB*2, 256, 0, stream>>>(target, emb, cw, cb, fxw, xtp);

    // head
    k_fc1<<<NB, 256, 0, stream>>>(gfc, xtp, fxb, f1w, f1b, hf1);
    k_fc2<<<NB, 256, 0, stream>>>(hf1, f2w, f2b, hf2);
    k_out<<<NB, 64, 0, stream>>>(hf2, ow, ob, (float*)d_out);
}

// Round 5
// 512.964 us; speedup vs baseline: 1.2371x; 1.0254x over previous
//
#include <hip/hip_runtime.h>
#include <hip/hip_bf16.h>

using bf16 = __hip_bfloat16;

#define NN 16384
#define NE 262144
#define ET (NE + NN)
#define NB 128
#define FEAT 78
#define HEADS 10
#define D1 780
#define OD 128
#define PL 1000
#define VOC 26
#define SLOPE 0.2f

// ---------------- CSR build ----------------
__global__ void k_hist(const int* __restrict__ ei, int* __restrict__ cnt){
    int e = blockIdx.x*256 + threadIdx.x;
    if (e >= ET) return;
    int dst = (e < NE) ? ei[NE + e] : (e - NE);
    atomicAdd(&cnt[dst], 1);
}

__global__ __launch_bounds__(1024) void k_scan(const int* __restrict__ cnt, int* __restrict__ off){
    __shared__ int ps[1024];
    int t = threadIdx.x;
    int loc[16]; int s = 0;
#pragma unroll
    for (int j = 0; j < 16; ++j){ loc[j] = cnt[t*16 + j]; s += loc[j]; }
    ps[t] = s; __syncthreads();
    for (int d = 1; d < 1024; d <<= 1){
        int v = (t >= d) ? ps[t - d] : 0;
        __syncthreads();
        ps[t] += v;
        __syncthreads();
    }
    int run = (t == 0) ? 0 : ps[t - 1];
#pragma unroll
    for (int j = 0; j < 16; ++j){ off[t*16 + j] = run; run += loc[j]; }
    if (t == 1023) off[NN] = run;
}

__global__ void k_fill(const int* __restrict__ ei, const int* __restrict__ off,
                       int* __restrict__ cur, int* __restrict__ csrc){
    int e = blockIdx.x*256 + threadIdx.x;
    if (e >= ET) return;
    int src, dst;
    if (e < NE){ src = ei[e]; dst = ei[NE + e]; } else { src = e - NE; dst = src; }
    int p = off[dst] + atomicAdd(&cur[dst], 1);
    csrc[p] = src;
}

// ---------------- GAT layer 1 (x-space) ----------------
__global__ __launch_bounds__(256) void k_va(const float* __restrict__ W1, const float* __restrict__ asw,
                                            const float* __restrict__ adw,
                                            float* __restrict__ vas, float* __restrict__ vad){
    __shared__ float sa[D1], sd[D1];
    int t = threadIdx.x;
    for (int i = t; i < D1; i += 256){ sa[i] = asw[i]; sd[i] = adw[i]; }
    __syncthreads();
    for (int idx = t; idx < D1; idx += 256){
        int h = idx / FEAT, k = idx % FEAT;
        const float* wr = W1 + (size_t)k*D1 + h*FEAT;
        float a = 0.f, d = 0.f;
        for (int j = 0; j < FEAT; ++j){ float w = wr[j]; a += w*sa[h*FEAT + j]; d += w*sd[h*FEAT + j]; }
        vas[idx] = a; vad[idx] = d;
    }
}

__global__ __launch_bounds__(256) void k_alpha1x(const float* __restrict__ x, const float* __restrict__ vas,
                                                 const float* __restrict__ vad,
                                                 float* __restrict__ as1, float* __restrict__ ad1){
    __shared__ float xs[64*79];
    __shared__ float va[D1], vd[D1];
    int n0 = blockIdx.x * 64, t = threadIdx.x;
    for (int i = t; i < D1; i += 256){ va[i] = vas[i]; vd[i] = vad[i]; }
    for (int i = t; i < 64*FEAT; i += 256){
        int n = i / FEAT, k = i % FEAT;
        xs[n*79 + k] = x[(size_t)n0*FEAT + i];
    }
    __syncthreads();
    for (int p = t; p < 64*HEADS; p += 256){
        int h = p >> 6, nl = p & 63;
        const float* xr = xs + nl*79;
        const float* pa = va + h*FEAT; const float* pd = vd + h*FEAT;
        float a = 0.f, d = 0.f;
        for (int k = 0; k < FEAT; ++k){ float xv = xr[k]; a += xv*pa[k]; d += xv*pd[k]; }
        as1[(size_t)(n0 + nl)*HEADS + h] = a;
        ad1[(size_t)(n0 + nl)*HEADS + h] = d;
    }
}

__global__ __launch_bounds__(64) void k_gat1x(const float* __restrict__ x, const float* __restrict__ as1,
                                              const float* __restrict__ ad1, const int* __restrict__ off,
                                              const int* __restrict__ csrc,
                                              float* __restrict__ agg){
    __shared__ float mh_l[HEADS], sv_l[HEADS];
    int dst = blockIdx.x, lane = threadIdx.x;
    int beg = off[dst], end = off[dst + 1];
    if (lane < HEADS){
        float adv = ad1[(size_t)dst*HEADS + lane];
        float m = -1e30f, sm = 0.f;
        for (int e = beg; e < end; ++e){
            int s = csrc[e];
            float v = as1[(size_t)s*HEADS + lane] + adv;
            v = v > 0.f ? v : SLOPE*v;
            float mn = fmaxf(m, v);
            sm = sm*__expf(m - mn) + __expf(v - mn);
            m = mn;
        }
        mh_l[lane] = m;
        sv_l[lane] = 1.f/(sm + 1e-16f);
    }
    __syncthreads();
    float mh[HEADS], sv[HEADS], adh[HEADS];
#pragma unroll
    for (int h = 0; h < HEADS; ++h){
        mh[h] = mh_l[h]; sv[h] = sv_l[h];
        adh[h] = ad1[(size_t)dst*HEADS + h];
    }
    float acc1[HEADS], acc2[HEADS];
#pragma unroll
    for (int h = 0; h < HEADS; ++h){ acc1[h] = 0.f; acc2[h] = 0.f; }
    for (int e = beg; e < end; ++e){
        int s = csrc[e];
        const float* xr = x + (size_t)s*FEAT;
        float xv1 = xr[lane];
        float xv2 = (lane < FEAT - 64) ? xr[64 + lane] : 0.f;
        float vv[HEADS];
#pragma unroll
        for (int h = 0; h < HEADS; ++h) vv[h] = as1[(size_t)s*HEADS + h];
#pragma unroll
        for (int h = 0; h < HEADS; ++h){
            float v = vv[h] + adh[h];
            v = v > 0.f ? v : SLOPE*v;
            float al = __expf(v - mh[h]) * sv[h];
            acc1[h] += al*xv1;
            acc2[h] += al*xv2;
        }
    }
#pragma unroll
    for (int h = 0; h < HEADS; ++h)
        agg[(size_t)dst*D1 + h*FEAT + lane] = acc1[h];
    if (lane < FEAT - 64){
#pragma unroll
        for (int h = 0; h < HEADS; ++h)
            agg[(size_t)dst*D1 + h*FEAT + 64 + lane] = acc2[h];
    }
}

__global__ __launch_bounds__(320) void k_post1(const float* __restrict__ agg, const float* __restrict__ W1,
                                               const float* __restrict__ b1, float* __restrict__ h1){
    __shared__ __align__(16) float ags[8][800];
    int r0 = blockIdx.x * 8, t = threadIdx.x;
    for (int i = t; i < 8*D1; i += 320){
        int r = i / D1, c = i % D1, h = c / FEAT, j = c % FEAT;
        ags[r][h*80 + j] = agg[(size_t)(r0 + r)*D1 + c];
    }
    __syncthreads();
    if (t < 260){
        int h = t / 26, jj = (t % 26)*3;
        int cb = h*FEAT + jj;
        const float* wcol = W1 + cb;
        float acc[8][3];
#pragma unroll
        for (int r = 0; r < 8; ++r){ acc[r][0] = 0.f; acc[r][1] = 0.f; acc[r][2] = 0.f; }
        int k = 0;
        for (; k + 4 <= FEAT; k += 4){
            float4 a[8];
#pragma unroll
            for (int r = 0; r < 8; ++r) a[r] = *(const float4*)&ags[r][h*80 + k];
#pragma unroll
            for (int kk = 0; kk < 4; ++kk){
                const float* wr = wcol + (size_t)(k + kk)*D1;
                float w0 = wr[0], w1 = wr[1], w2 = wr[2];
#pragma unroll
                for (int r = 0; r < 8; ++r){
                    float av = ((const float*)&a[r])[kk];
                    acc[r][0] += av*w0; acc[r][1] += av*w1; acc[r][2] += av*w2;
                }
            }
        }
        for (; k < FEAT; ++k){
            const float* wr = wcol + (size_t)k*D1;
            float w0 = wr[0], w1 = wr[1], w2 = wr[2];
#pragma unroll
            for (int r = 0; r < 8; ++r){
                float av = ags[r][h*80 + k];
                acc[r][0] += av*w0; acc[r][1] += av*w1; acc[r][2] += av*w2;
            }
        }
        float bv0 = b1[cb], bv1 = b1[cb+1], bv2 = b1[cb+2];
#pragma unroll
        for (int r = 0; r < 8; ++r){
            float v0 = acc[r][0] + bv0, v1 = acc[r][1] + bv1, v2 = acc[r][2] + bv2;
            v0 = v0 > 0.f ? v0 : __expf(v0) - 1.f;
            v1 = v1 > 0.f ? v1 : __expf(v1) - 1.f;
            v2 = v2 > 0.f ? v2 : __expf(v2) - 1.f;
            size_t base = (size_t)(r0 + r)*D1 + cb;
            h1[base] = v0; h1[base+1] = v1; h1[base+2] = v2;
        }
    }
}

// ---------------- GAT layer 2 ----------------
#define KC 39
__global__ __launch_bounds__(256) void k_gemm2(const float* __restrict__ h1, const float* __restrict__ W2,
                                               float* __restrict__ xl2){
    __shared__ __align__(16) float as[KC][36];
    __shared__ __align__(16) float ws[KC][128];
    int r0 = blockIdx.x * 32, t = threadIdx.x;
    int rg = t >> 5, jq = t & 31;
    float acc[4][4];
#pragma unroll
    for (int i = 0; i < 4; ++i)
#pragma unroll
        for (int j = 0; j < 4; ++j) acc[i][j] = 0.f;
    for (int kc = 0; kc < D1; kc += KC){
        for (int i = t; i < 32*KC; i += 256){
            int r = i / KC, k = i % KC;
            as[k][r] = h1[(size_t)(r0 + r)*D1 + kc + k];
        }
        for (int i = t; i < KC*128; i += 256){
            int k = i >> 7, j = i & 127;
            ws[k][j] = W2[(size_t)(kc + k)*OD + j];
        }
        __syncthreads();
        for (int k = 0; k < KC; ++k){
            float4 a4 = *(const float4*)&as[k][rg*4];
            float4 w4 = *(const float4*)&ws[k][jq*4];
            float av[4] = {a4.x, a4.y, a4.z, a4.w};
            float wv[4] = {w4.x, w4.y, w4.z, w4.w};
#pragma unroll
            for (int i = 0; i < 4; ++i)
#pragma unroll
                for (int j = 0; j < 4; ++j) acc[i][j] += av[i]*wv[j];
        }
        __syncthreads();
    }
#pragma unroll
    for (int i = 0; i < 4; ++i){
        float4 o4 = make_float4(acc[i][0], acc[i][1], acc[i][2], acc[i][3]);
        *(float4*)&xl2[(size_t)(r0 + rg*4 + i)*OD + jq*4] = o4;
    }
}

__global__ __launch_bounds__(64) void k_alpha2(const float* __restrict__ xl2, const float* __restrict__ s2w,
                                               const float* __restrict__ d2w,
                                               float* __restrict__ as2, float* __restrict__ ad2){
    int n = blockIdx.x, lane = threadIdx.x;
    float v0 = xl2[(size_t)n*OD + lane], v1 = xl2[(size_t)n*OD + 64 + lane];
    float a = v0*s2w[lane] + v1*s2w[64 + lane];
    float d = v0*d2w[lane] + v1*d2w[64 + lane];
    for (int o = 32; o; o >>= 1){ a += __shfl_xor(a, o); d += __shfl_xor(d, o); }
    if (lane == 0){ as2[n] = a; ad2[n] = d; }
}

__global__ __launch_bounds__(64) void k_gat2(const float* __restrict__ xl2, const float* __restrict__ as2,
                                             const float* __restrict__ ad2, const int* __restrict__ off,
                                             const int* __restrict__ csrc, const float* __restrict__ b2,
                                             float* __restrict__ h2){
    int dst = blockIdx.x, lane = threadIdx.x;
    int beg = off[dst], end = off[dst + 1];
    float ad = ad2[dst];
    float m = -1e30f, sm = 0.f;
    for (int e = beg + lane; e < end; e += 64){
        float v = as2[csrc[e]] + ad; v = v > 0.f ? v : SLOPE*v;
        m = fmaxf(m, v);
    }
    for (int o = 32; o; o >>= 1) m = fmaxf(m, __shfl_xor(m, o));
    for (int e = beg + lane; e < end; e += 64){
        float v = as2[csrc[e]] + ad; v = v > 0.f ? v : SLOPE*v;
        sm += __expf(v - m);
    }
    for (int o = 32; o; o >>= 1) sm += __shfl_xor(sm, o);
    float inv = 1.f / (sm + 1e-16f);
    float a0 = 0.f, a1 = 0.f;
    for (int e = beg; e < end; ++e){
        int s = csrc[e];
        float v = as2[s] + ad; v = v > 0.f ? v : SLOPE*v;
        float alw = __expf(v - m) * inv;
        a0 += alw * xl2[(size_t)s*OD + lane];
        a1 += alw * xl2[(size_t)s*OD + 64 + lane];
    }
    float o0 = a0 + b2[lane];      o0 = o0 > 0.f ? o0 : 0.f;
    float o1 = a1 + b2[64 + lane]; o1 = o1 > 0.f ? o1 : 0.f;
    h2[(size_t)dst*OD + lane] = o0;
    h2[(size_t)dst*OD + 64 + lane] = o1;
}

// ---------------- pooling + graph FC ----------------
__global__ __launch_bounds__(128) void k_pool(const float* __restrict__ h2, const int* __restrict__ batch,
                                              float* __restrict__ g){
    int b = blockIdx.x, t = threadIdx.x;
    int lo = 0, hi = NN;
    while (lo < hi){ int mid = (lo + hi) >> 1; if (batch[mid] < b) lo = mid + 1; else hi = mid; }
    int s0 = lo;
    lo = s0; hi = NN;
    while (lo < hi){ int mid = (lo + hi) >> 1; if (batch[mid] < b + 1) lo = mid + 1; else hi = mid; }
    int s1 = lo;
    float mx = 0.f;
    for (int n = s0; n < s1; ++n) mx = fmaxf(mx, h2[(size_t)n*OD + t]);
    g[b*OD + t] = mx;
}

__global__ __launch_bounds__(128) void k_fcg(const float* __restrict__ g, const float* __restrict__ w,
                                             const float* __restrict__ bias, float* __restrict__ gfc){
    __shared__ float row[OD];
    int b = blockIdx.x, j = threadIdx.x;
    row[j] = g[b*OD + j];
    __syncthreads();
    float acc = 0.f;
    for (int k = 0; k < OD; ++k) acc += row[k] * w[k*OD + j];
    acc += bias[j];
    gfc[b*OD + j] = acc > 0.f ? acc : 0.f;
}

// ---------------- protein branch (high-occupancy pipeline) ----------------
// wt[i][o*8+k] = convw[o][i][k]  (coalesced rows for the A-build)
__global__ __launch_bounds__(256) void k_wt(const float* __restrict__ convw, float* __restrict__ wt){
    int idx = blockIdx.x*256 + threadIdx.x;           // 256000 total
    int i = idx >> 8, ok = idx & 255;
    wt[idx] = convw[(size_t)(ok >> 3)*PL*8 + (size_t)i*8 + (ok & 7)];
}

// A[b][v][ok] = sum_{i: ts[i]==v} wt[i][ok]
__global__ __launch_bounds__(256) void k_abuild(const int* __restrict__ target, const float* __restrict__ wt,
                                                float* __restrict__ Ag){
    __shared__ float A[VOC][256];
    __shared__ int ts[PL];
    int b = blockIdx.x, t = threadIdx.x;
    for (int i = t; i < PL; i += 256) ts[i] = target[b*PL + i];
#pragma unroll
    for (int v = 0; v < VOC; ++v) A[v][t] = 0.f;
    __syncthreads();
    for (int i = 0; i < PL; i += 2){
        float w0 = wt[(size_t)i*256 + t];
        float w1 = wt[(size_t)(i+1)*256 + t];
        A[ts[i]][t]   += w0;
        A[ts[i+1]][t] += w1;
    }
    __syncthreads();
#pragma unroll
    for (int v = 0; v < VOC; ++v)
        Ag[((size_t)b*VOC + v)*256 + t] = A[v][t];
}

// c[b][o][p] = relu( sum_v sum_k A[b][v][o*8+k]*emb[v][p+k] + cb[o] ), block=(b,half)
__global__ __launch_bounds__(256) void k_conv(const float* __restrict__ Ag, const float* __restrict__ emb,
                                              const float* __restrict__ convb, float* __restrict__ cbuf){
    __shared__ float As[VOC][128];
    __shared__ float embs[VOC*128 + 16];
    int b = blockIdx.x >> 1, half = blockIdx.x & 1;
    int t = threadIdx.x;
    for (int i = t; i < VOC*128; i += 256){
        int v = i >> 7, c = i & 127;
        As[v][c] = Ag[((size_t)b*VOC + v)*256 + half*128 + c];
        embs[i] = emb[i];
    }
    if (t < 16) embs[VOC*128 + t] = 0.f;
    __syncthreads();
    int o_l = t >> 4, pg = t & 15, p0 = pg * 8;
    float accp[8];
#pragma unroll
    for (int i = 0; i < 8; ++i) accp[i] = 0.f;
    for (int v = 0; v < VOC; ++v){
        float w[15];
        const float* er = embs + v*128 + p0;
#pragma unroll
        for (int i = 0; i < 15; ++i) w[i] = er[i];
#pragma unroll
        for (int k2 = 0; k2 < 8; ++k2){
            float a = As[v][o_l*8 + k2];
#pragma unroll
            for (int j = 0; j < 8; ++j) accp[j] += a * w[j + k2];
        }
    }
    float cbv = convb[half*16 + o_l];
#pragma unroll
    for (int j = 0; j < 8; ++j){
        int p = p0 + j;
        if (p < 121){
            float v2 = accp[j] + cbv;
            cbuf[(size_t)b*3872 + (half*16 + o_l)*121 + p] = v2 > 0.f ? v2 : 0.f;
        }
    }
}

// xt partials: block=(kt 0..15, bt 0..7); K-chunk = 242, b-tile = 16
__global__ __launch_bounds__(256) void k_xt(const float* __restrict__ cbuf, const float* __restrict__ fxw,
                                            float* __restrict__ xtp){
    __shared__ float csh[16][242];
    int kt = blockIdx.x >> 3, bt = blockIdx.x & 7;
    int t = threadIdx.x;
    for (int i = t; i < 16*242; i += 256){
        int bb = i / 242, kk = i % 242;
        csh[bb][kk] = cbuf[(size_t)(bt*16 + bb)*3872 + kt*242 + kk];
    }
    __syncthreads();
    int j = t & 127, bh = t >> 7;
    float acc[8];
#pragma unroll
    for (int i = 0; i < 8; ++i) acc[i] = 0.f;
    for (int kk = 0; kk < 242; ++kk){
        float w = fxw[(size_t)(kt*242 + kk)*128 + j];
#pragma unroll
        for (int bb = 0; bb < 8; ++bb) acc[bb] += csh[bh*8 + bb][kk] * w;
    }
#pragma unroll
    for (int bb = 0; bb < 8; ++bb)
        xtp[(size_t)kt*NB*128 + (size_t)(bt*16 + bh*8 + bb)*128 + j] = acc[bb];
}

// ---------------- fused head ----------------
__global__ __launch_bounds__(256) void k_fc1(const float* __restrict__ gfc, const float* __restrict__ xtp,
                                             const float* __restrict__ fxb,
                                             const float* __restrict__ w, const float* __restrict__ bias,
                                             float* __restrict__ out){
    __shared__ float xc[256];
    int b = blockIdx.x, t = threadIdx.x;
    if (t < 128) xc[t] = gfc[b*OD + t];
    else {
        int j = t - 128;
        float s = fxb[j];
#pragma unroll
        for (int kt = 0; kt < 16; ++kt) s += xtp[(size_t)kt*NB*128 + (size_t)b*128 + j];
        xc[t] = s;
    }
    __syncthreads();
#pragma unroll
    for (int rep = 0; rep < 4; ++rep){
        int j = t + rep*256;
        float acc = 0.f;
        for (int k = 0; k < 256; ++k) acc += xc[k] * w[(size_t)k*1024 + j];
        acc += bias[j];
        out[b*1024 + j] = acc > 0.f ? acc : 0.f;
    }
}

__global__ __launch_bounds__(256) void k_fc2(const float* __restrict__ in, const float* __restrict__ w,
                                             const float* __restrict__ bias, float* __restrict__ out){
    __shared__ float row[1024];
    int b = blockIdx.x, t = threadIdx.x;
    for (int i = t; i < 1024; i += 256) row[i] = in[b*1024 + i];
    __syncthreads();
    float acc = 0.f;
    for (int k = 0; k < 1024; ++k) acc += row[k] * w[(size_t)k*256 + t];
    acc += bias[t];
    out[b*256 + t] = acc > 0.f ? acc : 0.f;
}

__global__ __launch_bounds__(64) void k_out(const float* __restrict__ in, const float* __restrict__ w,
                                            const float* __restrict__ bias, float* __restrict__ out){
    int b = blockIdx.x, lane = threadIdx.x;
    float acc = 0.f;
#pragma unroll
    for (int r = 0; r < 4; ++r){ int k = lane + r*64; acc += in[b*256 + k] * w[k]; }
    for (int o = 32; o; o >>= 1) acc += __shfl_xor(acc, o);
    if (lane == 0) out[b] = acc + bias[0];
}

extern "C" void kernel_launch(void* const* d_in, const int* in_sizes, int n_in,
                              void* d_out, int out_size, void* d_ws, size_t ws_size,
                              hipStream_t stream){
    const float* x    = (const float*)d_in[0];
    const int*  ei    = (const int*)d_in[1];
    const int*  batch = (const int*)d_in[2];
    const int*  target= (const int*)d_in[3];
    const float* W1   = (const float*)d_in[4];
    const float* as1w = (const float*)d_in[5];
    const float* ad1w = (const float*)d_in[6];
    const float* b1   = (const float*)d_in[7];
    const float* W2   = (const float*)d_in[8];
    const float* as2w = (const float*)d_in[9];
    const float* ad2w = (const float*)d_in[10];
    const float* b2   = (const float*)d_in[11];
    const float* fgw  = (const float*)d_in[12];
    const float* fgb  = (const float*)d_in[13];
    const float* emb  = (const float*)d_in[14];
    const float* cw   = (const float*)d_in[15];
    const float* cb   = (const float*)d_in[16];
    const float* fxw  = (const float*)d_in[17];
    const float* fxb  = (const float*)d_in[18];
    const float* f1w  = (const float*)d_in[19];
    const float* f1b  = (const float*)d_in[20];
    const float* f2w  = (const float*)d_in[21];
    const float* f2b  = (const float*)d_in[22];
    const float* ow   = (const float*)d_in[23];
    const float* ob   = (const float*)d_in[24];

    float* f = (float*)d_ws;
    size_t o = 0;
    float* agg = f + o; o += (size_t)NN*D1;
    float* h1  = f + o; o += (size_t)NN*D1;
    float* as1 = f + o; o += (size_t)NN*HEADS;
    float* ad1 = f + o; o += (size_t)NN*HEADS;
    float* xl2 = f + o; o += (size_t)NN*OD;
    float* h2  = f + o; o += (size_t)NN*OD;
    float* as2 = f + o; o += NN;
    float* ad2 = f + o; o += NN;
    float* g   = f + o; o += NB*OD;
    float* gfc = f + o; o += NB*OD;
    float* hf1 = f + o; o += NB*1024;
    float* hf2 = f + o; o += NB*256;
    float* vas = f + o; o += D1;
    float* vad = f + o; o += D1;
    float* wt  = f + o; o += (size_t)PL*256;
    float* Ag  = f + o; o += (size_t)NB*VOC*256;
    float* cbuf= f + o; o += (size_t)NB*3872;
    float* xtp = f + o; o += (size_t)16*NB*128;
    int* cnt   = (int*)(f + o); o += NN;
    int* off   = (int*)(f + o); o += NN + 1;
    int* csrc  = (int*)(f + o); o += ET;
    (void)ws_size; (void)in_sizes; (void)n_in; (void)out_size;

    // CSR by destination
    hipMemsetAsync(cnt, 0, NN*sizeof(int), stream);
    k_hist<<<(ET + 255)/256, 256, 0, stream>>>(ei, cnt);
    k_scan<<<1, 1024, 0, stream>>>(cnt, off);
    hipMemsetAsync(cnt, 0, NN*sizeof(int), stream);
    k_fill<<<(ET + 255)/256, 256, 0, stream>>>(ei, off, cnt, csrc);

    // GAT layer 1 in x-space
    k_va<<<1, 256, 0, stream>>>(W1, as1w, ad1w, vas, vad);
    k_alpha1x<<<NN/64, 256, 0, stream>>>(x, vas, vad, as1, ad1);
    k_gat1x<<<NN, 64, 0, stream>>>(x, as1, ad1, off, csrc, agg);
    k_post1<<<NN/8, 320, 0, stream>>>(agg, W1, b1, h1);

    // GAT layer 2
    k_gemm2<<<NN/32, 256, 0, stream>>>(h1, W2, xl2);
    k_alpha2<<<NN, 64, 0, stream>>>(xl2, as2w, ad2w, as2, ad2);
    k_gat2<<<NN, 64, 0, stream>>>(xl2, as2, ad2, off, csrc, b2, h2);

    // pooling + graph fc
    k_pool<<<NB, 128, 0, stream>>>(h2, batch, g);
    k_fcg<<<NB, 128, 0, stream>>>(g, fgw, fgb, gfc);

    // protein branch
    k_wt<<<1000, 256, 0, stream>>>(cw, wt);
    k_abuild<<<NB, 256, 0, stream>>>(target, wt, Ag);
    k_conv<<<NB*2, 256, 0, stream>>>(Ag, emb, cb, cbuf);
    k_xt<<<128, 256, 0, stream>>>(cbuf, fxw, xtp);

    // head
    k_fc1<<<NB, 256, 0, stream>>>(gfc, xtp, fxb, f1w, f1b, hf1);
    k_fc2<<<NB, 256, 0, stream>>>(hf1, f2w, f2b, hf2);
    k_out<<<NB, 64, 0, stream>>>(hf2, ow, ob, (float*)d_out);
}

// Round 6
// 482.378 us; speedup vs baseline: 1.3155x; 1.0634x over previous
//
#include <hip/hip_runtime.h>
#include <hip/hip_bf16.h>

using bf16 = __hip_bfloat16;

#define NN 16384
#define NE 262144
#define ET (NE + NN)
#define NB 128
#define FEAT 78
#define HEADS 10
#define D1 780
#define OD 128
#define PL 1000
#define VOC 26
#define SLOPE 0.2f

// ---------------- CSR build ----------------
__global__ void k_hist(const int* __restrict__ ei, int* __restrict__ cnt){
    int e = blockIdx.x*256 + threadIdx.x;
    if (e >= ET) return;
    int dst = (e < NE) ? ei[NE + e] : (e - NE);
    atomicAdd(&cnt[dst], 1);
}

__global__ __launch_bounds__(1024) void k_scan(const int* __restrict__ cnt, int* __restrict__ off){
    __shared__ int ps[1024];
    int t = threadIdx.x;
    int loc[16]; int s = 0;
#pragma unroll
    for (int j = 0; j < 16; ++j){ loc[j] = cnt[t*16 + j]; s += loc[j]; }
    ps[t] = s; __syncthreads();
    for (int d = 1; d < 1024; d <<= 1){
        int v = (t >= d) ? ps[t - d] : 0;
        __syncthreads();
        ps[t] += v;
        __syncthreads();
    }
    int run = (t == 0) ? 0 : ps[t - 1];
#pragma unroll
    for (int j = 0; j < 16; ++j){ off[t*16 + j] = run; run += loc[j]; }
    if (t == 1023) off[NN] = run;
}

__global__ void k_fill(const int* __restrict__ ei, const int* __restrict__ off,
                       int* __restrict__ cur, int* __restrict__ csrc){
    int e = blockIdx.x*256 + threadIdx.x;
    if (e >= ET) return;
    int src, dst;
    if (e < NE){ src = ei[e]; dst = ei[NE + e]; } else { src = e - NE; dst = src; }
    int p = off[dst] + atomicAdd(&cur[dst], 1);
    csrc[p] = src;
}

// ---------------- GAT layer 1 (x-space) ----------------
__global__ __launch_bounds__(256) void k_va(const float* __restrict__ W1, const float* __restrict__ asw,
                                            const float* __restrict__ adw,
                                            float* __restrict__ vas, float* __restrict__ vad){
    __shared__ float sa[D1], sd[D1];
    int t = threadIdx.x;
    for (int i = t; i < D1; i += 256){ sa[i] = asw[i]; sd[i] = adw[i]; }
    __syncthreads();
    for (int idx = t; idx < D1; idx += 256){
        int h = idx / FEAT, k = idx % FEAT;
        const float* wr = W1 + (size_t)k*D1 + h*FEAT;
        float a = 0.f, d = 0.f;
        for (int j = 0; j < FEAT; ++j){ float w = wr[j]; a += w*sa[h*FEAT + j]; d += w*sd[h*FEAT + j]; }
        vas[idx] = a; vad[idx] = d;
    }
}

__global__ __launch_bounds__(256) void k_alpha1x(const float* __restrict__ x, const float* __restrict__ vas,
                                                 const float* __restrict__ vad,
                                                 float* __restrict__ as1, float* __restrict__ ad1){
    __shared__ float xs[64*79];
    __shared__ float va[D1], vd[D1];
    int n0 = blockIdx.x * 64, t = threadIdx.x;
    for (int i = t; i < D1; i += 256){ va[i] = vas[i]; vd[i] = vad[i]; }
    for (int i = t; i < 64*FEAT; i += 256){
        int n = i / FEAT, k = i % FEAT;
        xs[n*79 + k] = x[(size_t)n0*FEAT + i];
    }
    __syncthreads();
    for (int p = t; p < 64*HEADS; p += 256){
        int h = p >> 6, nl = p & 63;
        const float* xr = xs + nl*79;
        const float* pa = va + h*FEAT; const float* pd = vd + h*FEAT;
        float a = 0.f, d = 0.f;
        for (int k = 0; k < FEAT; ++k){ float xv = xr[k]; a += xv*pa[k]; d += xv*pd[k]; }
        as1[(size_t)(n0 + nl)*HEADS + h] = a;
        ad1[(size_t)(n0 + nl)*HEADS + h] = d;
    }
}

__global__ __launch_bounds__(64) void k_gat1x(const float* __restrict__ x, const float* __restrict__ as1,
                                              const float* __restrict__ ad1, const int* __restrict__ off,
                                              const int* __restrict__ csrc,
                                              float* __restrict__ agg){
    __shared__ float mh_l[HEADS], sv_l[HEADS];
    int dst = blockIdx.x, lane = threadIdx.x;
    int beg = off[dst], end = off[dst + 1];
    if (lane < HEADS){
        float adv = ad1[(size_t)dst*HEADS + lane];
        float m = -1e30f, sm = 0.f;
        for (int e = beg; e < end; ++e){
            int s = csrc[e];
            float v = as1[(size_t)s*HEADS + lane] + adv;
            v = v > 0.f ? v : SLOPE*v;
            float mn = fmaxf(m, v);
            sm = sm*__expf(m - mn) + __expf(v - mn);
            m = mn;
        }
        mh_l[lane] = m;
        sv_l[lane] = 1.f/(sm + 1e-16f);
    }
    __syncthreads();
    float mh[HEADS], sv[HEADS], adh[HEADS];
#pragma unroll
    for (int h = 0; h < HEADS; ++h){
        mh[h] = mh_l[h]; sv[h] = sv_l[h];
        adh[h] = ad1[(size_t)dst*HEADS + h];
    }
    float acc1[HEADS], acc2[HEADS];
#pragma unroll
    for (int h = 0; h < HEADS; ++h){ acc1[h] = 0.f; acc2[h] = 0.f; }
    for (int e = beg; e < end; ++e){
        int s = csrc[e];
        const float* xr = x + (size_t)s*FEAT;
        float xv1 = xr[lane];
        float xv2 = (lane < FEAT - 64) ? xr[64 + lane] : 0.f;
        float vv[HEADS];
#pragma unroll
        for (int h = 0; h < HEADS; ++h) vv[h] = as1[(size_t)s*HEADS + h];
#pragma unroll
        for (int h = 0; h < HEADS; ++h){
            float v = vv[h] + adh[h];
            v = v > 0.f ? v : SLOPE*v;
            float al = __expf(v - mh[h]) * sv[h];
            acc1[h] += al*xv1;
            acc2[h] += al*xv2;
        }
    }
#pragma unroll
    for (int h = 0; h < HEADS; ++h)
        agg[(size_t)dst*D1 + h*FEAT + lane] = acc1[h];
    if (lane < FEAT - 64){
#pragma unroll
        for (int h = 0; h < HEADS; ++h)
            agg[(size_t)dst*D1 + h*FEAT + 64 + lane] = acc2[h];
    }
}

__global__ __launch_bounds__(320) void k_post1(const float* __restrict__ agg, const float* __restrict__ W1,
                                               const float* __restrict__ b1, float* __restrict__ h1){
    __shared__ __align__(16) float ags[8][800];
    int r0 = blockIdx.x * 8, t = threadIdx.x;
    for (int i = t; i < 8*D1; i += 320){
        int r = i / D1, c = i % D1, h = c / FEAT, j = c % FEAT;
        ags[r][h*80 + j] = agg[(size_t)(r0 + r)*D1 + c];
    }
    __syncthreads();
    if (t < 260){
        int h = t / 26, jj = (t % 26)*3;
        int cb = h*FEAT + jj;
        const float* wcol = W1 + cb;
        float acc[8][3];
#pragma unroll
        for (int r = 0; r < 8; ++r){ acc[r][0] = 0.f; acc[r][1] = 0.f; acc[r][2] = 0.f; }
        int k = 0;
        for (; k + 4 <= FEAT; k += 4){
            float4 a[8];
#pragma unroll
            for (int r = 0; r < 8; ++r) a[r] = *(const float4*)&ags[r][h*80 + k];
#pragma unroll
            for (int kk = 0; kk < 4; ++kk){
                const float* wr = wcol + (size_t)(k + kk)*D1;
                float w0 = wr[0], w1 = wr[1], w2 = wr[2];
#pragma unroll
                for (int r = 0; r < 8; ++r){
                    float av = ((const float*)&a[r])[kk];
                    acc[r][0] += av*w0; acc[r][1] += av*w1; acc[r][2] += av*w2;
                }
            }
        }
        for (; k < FEAT; ++k){
            const float* wr = wcol + (size_t)k*D1;
            float w0 = wr[0], w1 = wr[1], w2 = wr[2];
#pragma unroll
            for (int r = 0; r < 8; ++r){
                float av = ags[r][h*80 + k];
                acc[r][0] += av*w0; acc[r][1] += av*w1; acc[r][2] += av*w2;
            }
        }
        float bv0 = b1[cb], bv1 = b1[cb+1], bv2 = b1[cb+2];
#pragma unroll
        for (int r = 0; r < 8; ++r){
            float v0 = acc[r][0] + bv0, v1 = acc[r][1] + bv1, v2 = acc[r][2] + bv2;
            v0 = v0 > 0.f ? v0 : __expf(v0) - 1.f;
            v1 = v1 > 0.f ? v1 : __expf(v1) - 1.f;
            v2 = v2 > 0.f ? v2 : __expf(v2) - 1.f;
            size_t base = (size_t)(r0 + r)*D1 + cb;
            h1[base] = v0; h1[base+1] = v1; h1[base+2] = v2;
        }
    }
}

// ---------------- GAT layer 2 GEMM: K-split x4 ----------------
#define KC 39
#define KS 4
#define KSEG 195
__global__ __launch_bounds__(256) void k_gemm2(const float* __restrict__ h1, const float* __restrict__ W2,
                                               float* __restrict__ xlp){
    __shared__ __align__(16) float as[KC][40];
    __shared__ __align__(16) float ws[KC][128];
    int bid = blockIdx.x;
    int ks = bid & (KS - 1);
    int r0 = (bid >> 2) * 32;
    int t = threadIdx.x;
    int rg = t >> 5, jq = t & 31;
    float acc[4][4];
#pragma unroll
    for (int i = 0; i < 4; ++i)
#pragma unroll
        for (int j = 0; j < 4; ++j) acc[i][j] = 0.f;
    for (int kc = ks*KSEG; kc < ks*KSEG + KSEG; kc += KC){
        for (int i = t; i < 32*KC; i += 256){
            int r = i / KC, k = i % KC;
            as[k][r] = h1[(size_t)(r0 + r)*D1 + kc + k];
        }
        for (int i = t; i < KC*128; i += 256){
            int k = i >> 7, j = i & 127;
            ws[k][j] = W2[(size_t)(kc + k)*OD + j];
        }
        __syncthreads();
        for (int k = 0; k < KC; ++k){
            float4 a4 = *(const float4*)&as[k][rg*4];
            float4 w4 = *(const float4*)&ws[k][jq*4];
            float av[4] = {a4.x, a4.y, a4.z, a4.w};
            float wv[4] = {w4.x, w4.y, w4.z, w4.w};
#pragma unroll
            for (int i = 0; i < 4; ++i)
#pragma unroll
                for (int j = 0; j < 4; ++j) acc[i][j] += av[i]*wv[j];
        }
        __syncthreads();
    }
    float* dst = xlp + (size_t)ks*NN*OD;
#pragma unroll
    for (int i = 0; i < 4; ++i){
        float4 o4 = make_float4(acc[i][0], acc[i][1], acc[i][2], acc[i][3]);
        *(float4*)&dst[(size_t)(r0 + rg*4 + i)*OD + jq*4] = o4;
    }
}

// reduce 4 partials -> xl2, fused alpha2 (per-row dots with s2w/d2w)
__global__ __launch_bounds__(128) void k_red(const float* __restrict__ xlp,
                                             const float* __restrict__ s2w, const float* __restrict__ d2w,
                                             float* __restrict__ xl2,
                                             float* __restrict__ as2, float* __restrict__ ad2){
    const size_t Q = (size_t)NN*OD/4;
    int t = threadIdx.x;
    size_t fi = (size_t)blockIdx.x*128 + t;
    const float4* P = (const float4*)xlp;
    float4 a = P[fi], b = P[fi + Q], c = P[fi + 2*Q], d = P[fi + 3*Q];
    float4 v = make_float4(a.x+b.x+c.x+d.x, a.y+b.y+c.y+d.y,
                           a.z+b.z+c.z+d.z, a.w+b.w+c.w+d.w);
    ((float4*)xl2)[fi] = v;
    int cc = (t & 31)*4;
    float sa = v.x*s2w[cc] + v.y*s2w[cc+1] + v.z*s2w[cc+2] + v.w*s2w[cc+3];
    float sd = v.x*d2w[cc] + v.y*d2w[cc+1] + v.z*d2w[cc+2] + v.w*d2w[cc+3];
#pragma unroll
    for (int o = 16; o; o >>= 1){ sa += __shfl_xor(sa, o); sd += __shfl_xor(sd, o); }
    if ((t & 31) == 0){
        int n = blockIdx.x*4 + (t >> 5);
        as2[n] = sa; ad2[n] = sd;
    }
}

__global__ __launch_bounds__(64) void k_gat2(const float* __restrict__ xl2, const float* __restrict__ as2,
                                             const float* __restrict__ ad2, const int* __restrict__ off,
                                             const int* __restrict__ csrc, const float* __restrict__ b2,
                                             float* __restrict__ h2){
    int dst = blockIdx.x, lane = threadIdx.x;
    int beg = off[dst], end = off[dst + 1];
    float ad = ad2[dst];
    float m = -1e30f, sm = 0.f;
    for (int e = beg + lane; e < end; e += 64){
        float v = as2[csrc[e]] + ad; v = v > 0.f ? v : SLOPE*v;
        m = fmaxf(m, v);
    }
    for (int o = 32; o; o >>= 1) m = fmaxf(m, __shfl_xor(m, o));
    for (int e = beg + lane; e < end; e += 64){
        float v = as2[csrc[e]] + ad; v = v > 0.f ? v : SLOPE*v;
        sm += __expf(v - m);
    }
    for (int o = 32; o; o >>= 1) sm += __shfl_xor(sm, o);
    float inv = 1.f / (sm + 1e-16f);
    float a0 = 0.f, a1 = 0.f;
    for (int e = beg; e < end; ++e){
        int s = csrc[e];
        float v = as2[s] + ad; v = v > 0.f ? v : SLOPE*v;
        float alw = __expf(v - m) * inv;
        a0 += alw * xl2[(size_t)s*OD + lane];
        a1 += alw * xl2[(size_t)s*OD + 64 + lane];
    }
    float o0 = a0 + b2[lane];      o0 = o0 > 0.f ? o0 : 0.f;
    float o1 = a1 + b2[64 + lane]; o1 = o1 > 0.f ? o1 : 0.f;
    h2[(size_t)dst*OD + lane] = o0;
    h2[(size_t)dst*OD + 64 + lane] = o1;
}

// ---------------- pooling + graph FC (fused) ----------------
__global__ __launch_bounds__(128) void k_poolfc(const float* __restrict__ h2, const int* __restrict__ batch,
                                                const float* __restrict__ w, const float* __restrict__ bias,
                                                float* __restrict__ gfc){
    __shared__ float row[OD];
    int b = blockIdx.x, t = threadIdx.x;
    int lo = 0, hi = NN;
    while (lo < hi){ int mid = (lo + hi) >> 1; if (batch[mid] < b) lo = mid + 1; else hi = mid; }
    int s0 = lo;
    lo = s0; hi = NN;
    while (lo < hi){ int mid = (lo + hi) >> 1; if (batch[mid] < b + 1) lo = mid + 1; else hi = mid; }
    int s1 = lo;
    float mx = 0.f;
    for (int n = s0; n < s1; ++n) mx = fmaxf(mx, h2[(size_t)n*OD + t]);
    row[t] = mx;
    __syncthreads();
    float acc = 0.f;
    for (int k = 0; k < OD; ++k) acc += row[k] * w[k*OD + t];
    acc += bias[t];
    gfc[b*OD + t] = acc > 0.f ? acc : 0.f;
}

// ---------------- protein branch ----------------
// A[b][v][ok] = sum_{i: ts[i]==v} convw[o][i][k], ok = o*8+k (direct, no transpose buffer)
__global__ __launch_bounds__(256) void k_abuild(const int* __restrict__ target, const float* __restrict__ convw,
                                                float* __restrict__ Ag){
    __shared__ float A[VOC][256];
    __shared__ int ts[PL];
    int b = blockIdx.x, t = threadIdx.x;
    for (int i = t; i < PL; i += 256) ts[i] = target[b*PL + i];
#pragma unroll
    for (int v = 0; v < VOC; ++v) A[v][t] = 0.f;
    __syncthreads();
    const float* wp = convw + (size_t)(t >> 3)*PL*8 + (t & 7);
    for (int i = 0; i < PL; i += 2){
        float w0 = wp[(size_t)i*8];
        float w1 = wp[(size_t)(i+1)*8];
        A[ts[i]][t]   += w0;
        A[ts[i+1]][t] += w1;
    }
    __syncthreads();
#pragma unroll
    for (int v = 0; v < VOC; ++v)
        Ag[((size_t)b*VOC + v)*256 + t] = A[v][t];
}

__global__ __launch_bounds__(256) void k_conv(const float* __restrict__ Ag, const float* __restrict__ emb,
                                              const float* __restrict__ convb, float* __restrict__ cbuf){
    __shared__ float As[VOC][128];
    __shared__ float embs[VOC*128 + 16];
    int b = blockIdx.x >> 1, half = blockIdx.x & 1;
    int t = threadIdx.x;
    for (int i = t; i < VOC*128; i += 256){
        int v = i >> 7, c = i & 127;
        As[v][c] = Ag[((size_t)b*VOC + v)*256 + half*128 + c];
        embs[i] = emb[i];
    }
    if (t < 16) embs[VOC*128 + t] = 0.f;
    __syncthreads();
    int o_l = t >> 4, pg = t & 15, p0 = pg * 8;
    float accp[8];
#pragma unroll
    for (int i = 0; i < 8; ++i) accp[i] = 0.f;
    for (int v = 0; v < VOC; ++v){
        float w[15];
        const float* er = embs + v*128 + p0;
#pragma unroll
        for (int i = 0; i < 15; ++i) w[i] = er[i];
#pragma unroll
        for (int k2 = 0; k2 < 8; ++k2){
            float a = As[v][o_l*8 + k2];
#pragma unroll
            for (int j = 0; j < 8; ++j) accp[j] += a * w[j + k2];
        }
    }
    float cbv = convb[half*16 + o_l];
#pragma unroll
    for (int j = 0; j < 8; ++j){
        int p = p0 + j;
        if (p < 121){
            float v2 = accp[j] + cbv;
            cbuf[(size_t)b*3872 + (half*16 + o_l)*121 + p] = v2 > 0.f ? v2 : 0.f;
        }
    }
}

__global__ __launch_bounds__(256) void k_xt(const float* __restrict__ cbuf, const float* __restrict__ fxw,
                                            float* __restrict__ xtp){
    __shared__ float csh[16][242];
    int kt = blockIdx.x >> 3, bt = blockIdx.x & 7;
    int t = threadIdx.x;
    for (int i = t; i < 16*242; i += 256){
        int bb = i / 242, kk = i % 242;
        csh[bb][kk] = cbuf[(size_t)(bt*16 + bb)*3872 + kt*242 + kk];
    }
    __syncthreads();
    int j = t & 127, bh = t >> 7;
    float acc[8];
#pragma unroll
    for (int i = 0; i < 8; ++i) acc[i] = 0.f;
    for (int kk = 0; kk < 242; ++kk){
        float w = fxw[(size_t)(kt*242 + kk)*128 + j];
#pragma unroll
        for (int bb = 0; bb < 8; ++bb) acc[bb] += csh[bh*8 + bb][kk] * w;
    }
#pragma unroll
    for (int bb = 0; bb < 8; ++bb)
        xtp[(size_t)kt*NB*128 + (size_t)(bt*16 + bh*8 + bb)*128 + j] = acc[bb];
}

// ---------------- fused head ----------------
__global__ __launch_bounds__(256) void k_fc1(const float* __restrict__ gfc, const float* __restrict__ xtp,
                                             const float* __restrict__ fxb,
                                             const float* __restrict__ w, const float* __restrict__ bias,
                                             float* __restrict__ out){
    __shared__ float xc[256];
    int b = blockIdx.x, t = threadIdx.x;
    if (t < 128) xc[t] = gfc[b*OD + t];
    else {
        int j = t - 128;
        float s = fxb[j];
#pragma unroll
        for (int kt = 0; kt < 16; ++kt) s += xtp[(size_t)kt*NB*128 + (size_t)b*128 + j];
        xc[t] = s;
    }
    __syncthreads();
#pragma unroll
    for (int rep = 0; rep < 4; ++rep){
        int j = t + rep*256;
        float acc = 0.f;
        for (int k = 0; k < 256; ++k) acc += xc[k] * w[(size_t)k*1024 + j];
        acc += bias[j];
        out[b*1024 + j] = acc > 0.f ? acc : 0.f;
    }
}

// fc2 + out fused: compute hf2 row in LDS, dot with out weights
__global__ __launch_bounds__(256) void k_fc2o(const float* __restrict__ in, const float* __restrict__ w,
                                              const float* __restrict__ bias, const float* __restrict__ ow,
                                              const float* __restrict__ ob, float* __restrict__ out){
    __shared__ float row[1024];
    __shared__ float s2[256];
    int b = blockIdx.x, t = threadIdx.x;
    for (int i = t; i < 1024; i += 256) row[i] = in[b*1024 + i];
    __syncthreads();
    float acc = 0.f;
    for (int k = 0; k < 1024; ++k) acc += row[k] * w[(size_t)k*256 + t];
    acc += bias[t];
    acc = acc > 0.f ? acc : 0.f;
    s2[t] = acc * ow[t];
    __syncthreads();
    if (t < 64){
        float a = s2[t] + s2[t + 64] + s2[t + 128] + s2[t + 192];
#pragma unroll
        for (int o = 32; o; o >>= 1) a += __shfl_xor(a, o);
        if (t == 0) out[b] = a + ob[0];
    }
}

extern "C" void kernel_launch(void* const* d_in, const int* in_sizes, int n_in,
                              void* d_out, int out_size, void* d_ws, size_t ws_size,
                              hipStream_t stream){
    const float* x    = (const float*)d_in[0];
    const int*  ei    = (const int*)d_in[1];
    const int*  batch = (const int*)d_in[2];
    const int*  target= (const int*)d_in[3];
    const float* W1   = (const float*)d_in[4];
    const float* as1w = (const float*)d_in[5];
    const float* ad1w = (const float*)d_in[6];
    const float* b1   = (const float*)d_in[7];
    const float* W2   = (const float*)d_in[8];
    const float* as2w = (const float*)d_in[9];
    const float* ad2w = (const float*)d_in[10];
    const float* b2   = (const float*)d_in[11];
    const float* fgw  = (const float*)d_in[12];
    const float* fgb  = (const float*)d_in[13];
    const float* emb  = (const float*)d_in[14];
    const float* cw   = (const float*)d_in[15];
    const float* cb   = (const float*)d_in[16];
    const float* fxw  = (const float*)d_in[17];
    const float* fxb  = (const float*)d_in[18];
    const float* f1w  = (const float*)d_in[19];
    const float* f1b  = (const float*)d_in[20];
    const float* f2w  = (const float*)d_in[21];
    const float* f2b  = (const float*)d_in[22];
    const float* ow   = (const float*)d_in[23];
    const float* ob   = (const float*)d_in[24];

    float* f = (float*)d_ws;
    size_t o = 0;
    float* agg = f + o; o += (size_t)NN*D1;     // also reused as xlp (4*NN*OD <= NN*D1)
    float* h1  = f + o; o += (size_t)NN*D1;
    float* as1 = f + o; o += (size_t)NN*HEADS;
    float* ad1 = f + o; o += (size_t)NN*HEADS;
    float* xl2 = f + o; o += (size_t)NN*OD;
    float* h2  = f + o; o += (size_t)NN*OD;
    float* as2 = f + o; o += NN;
    float* ad2 = f + o; o += NN;
    float* gfc = f + o; o += NB*OD;
    float* hf1 = f + o; o += NB*1024;
    float* vas = f + o; o += D1;
    float* vad = f + o; o += D1;
    float* Ag  = f + o; o += (size_t)NB*VOC*256;
    float* cbuf= f + o; o += (size_t)NB*3872;
    float* xtp = f + o; o += (size_t)16*NB*128;
    int* cnt   = (int*)(f + o); o += NN;
    int* off   = (int*)(f + o); o += NN + 1;
    int* csrc  = (int*)(f + o); o += ET;
    float* xlp = agg;  // agg is dead after k_post1; 4 partials of NN*OD fit in NN*D1
    (void)ws_size; (void)in_sizes; (void)n_in; (void)out_size;

    // CSR by destination
    hipMemsetAsync(cnt, 0, NN*sizeof(int), stream);
    k_hist<<<(ET + 255)/256, 256, 0, stream>>>(ei, cnt);
    k_scan<<<1, 1024, 0, stream>>>(cnt, off);
    hipMemsetAsync(cnt, 0, NN*sizeof(int), stream);
    k_fill<<<(ET + 255)/256, 256, 0, stream>>>(ei, off, cnt, csrc);

    // GAT layer 1 in x-space
    k_va<<<1, 256, 0, stream>>>(W1, as1w, ad1w, vas, vad);
    k_alpha1x<<<NN/64, 256, 0, stream>>>(x, vas, vad, as1, ad1);
    k_gat1x<<<NN, 64, 0, stream>>>(x, as1, ad1, off, csrc, agg);
    k_post1<<<NN/8, 320, 0, stream>>>(agg, W1, b1, h1);

    // GAT layer 2 (K-split GEMM + fused reduce/alpha2)
    k_gemm2<<<(NN/32)*KS, 256, 0, stream>>>(h1, W2, xlp);
    k_red<<<NN/4, 128, 0, stream>>>(xlp, as2w, ad2w, xl2, as2, ad2);
    k_gat2<<<NN, 64, 0, stream>>>(xl2, as2, ad2, off, csrc, b2, h2);

    // pooling + graph fc (fused)
    k_poolfc<<<NB, 128, 0, stream>>>(h2, batch, fgw, fgb, gfc);

    // protein branch
    k_abuild<<<NB, 256, 0, stream>>>(target, cw, Ag);
    k_conv<<<NB*2, 256, 0, stream>>>(Ag, emb, cb, cbuf);
    k_xt<<<128, 256, 0, stream>>>(cbuf, fxw, xtp);

    // head
    k_fc1<<<NB, 256, 0, stream>>>(gfc, xtp, fxb, f1w, f1b, hf1);
    k_fc2o<<<NB, 256, 0, stream>>>(hf1, f2w, f2b, ow, ob, (float*)d_out);
}